// Round 6
// baseline (168.783 us; speedup 1.0000x reference)
//
#include <hip/hip_runtime.h>
#include <hip/hip_fp16.h>

// ---------------------------------------------------------------------------
// ClassificationKNNLoss on MI355X — fused, distance matrix never materialized.
//   k_prep : norms + bf16 convert with granule-XOR swizzle
//   k_samp : MFMA GEMM over 512 sampled cols/row -> f16 distances
//   k_tau  : per-row 6th-smallest sample = conservative threshold tau
//   k_main : full GEMM, BARRIER-FREE — B-fragments gathered directly from
//            global (xb L2-resident; per-lane offsets constant across tiles).
//            R5 lesson: counted-vmcnt pipelining changed nothing -> staging
//            was never the stall; per-tile 8-wave barriers + 70KB LDS
//            residency were. Now LDS = 4.5KB, 2 barriers total.
//   k_fin  : per-row top-16 of passers, label match, loss reduction
// ---------------------------------------------------------------------------

typedef __attribute__((ext_vector_type(8))) short s8v;    // 8 x bf16 (4 VGPR)
typedef __attribute__((ext_vector_type(4))) float f32x4;  // MFMA acc

#define NROW 8192
#define NK   256
#define SAMPN 512
#define TAUR  6    // tau = 6th smallest of 512 samples -> E[passers/row] = 96
#define PSLOT 2    // slots per (row, 64-col tile, cf16)

template <bool B> struct BoolC { static constexpr bool value = B; };

// ws byte offsets
#define OFF_DNP  0                          // f32[8192*8] denom partials (256KB)
#define OFF_NRM  262144                     // f32[8192]
#define OFF_TAU  294912                     // u32[8192]
#define OFF_XB   327680                     // u16[8192*256] swizzled bf16 (4.19MB)
#define OFF_SAMP 4521984                    // u16[8192*512] (8.4MB); reused as
#define OFF_PASS 4521984                    // u32[8192*512] passers (16.8MB)
#define PASS_BYTES (NROW * 512 * 4)

__device__ __forceinline__ unsigned short f2bf(float f) {
  unsigned u = __float_as_uint(f);
  return (unsigned short)((u + 0x7FFFu + ((u >> 16) & 1u)) >> 16);  // RNE
}

__device__ __forceinline__ void gld16(const void* g, void* l) {
  __builtin_amdgcn_global_load_lds(
      (const __attribute__((address_space(1))) unsigned int*)g,
      (__attribute__((address_space(3))) unsigned int*)l, 16, 0, 0);
}

__device__ __forceinline__ unsigned umin32(unsigned a, unsigned b) { return a < b ? a : b; }

// ---------------------------------------------------------------- k_prep ----
// xb[(r,k)] stored at u16 index r*256 + ((k>>3) ^ (r&7))*8 + (k&7)
__global__ __launch_bounds__(256) void k_prep(const float* __restrict__ x,
                                              unsigned short* __restrict__ xb,
                                              float* __restrict__ nrm) {
  const int w = threadIdx.x >> 6, l = threadIdx.x & 63;
  const int r = blockIdx.x * 4 + w;
  const float4 xv = *reinterpret_cast<const float4*>(x + r * NK + l * 4);
  float ns = xv.x * xv.x + xv.y * xv.y + xv.z * xv.z + xv.w * xv.w;
  ns += __shfl_xor(ns, 1);  ns += __shfl_xor(ns, 2);  ns += __shfl_xor(ns, 4);
  ns += __shfl_xor(ns, 8);  ns += __shfl_xor(ns, 16); ns += __shfl_xor(ns, 32);
  if (l == 0) nrm[r] = ns;
  ushort4 bv;
  bv.x = f2bf(xv.x); bv.y = f2bf(xv.y); bv.z = f2bf(xv.z); bv.w = f2bf(xv.w);
  const int gs = (l >> 1) ^ (r & 7);
  *reinterpret_cast<ushort4*>(xb + r * NK + gs * 8 + (l & 1) * 4) = bv;
}

// ---------------------------------------------------------------- k_samp ----
// Sample s (0..511) -> global row j(s) = 16s + (s&7) ((j&7)==(s&7) keeps the
// granule swizzle consistent with tile position). One 64-sample tile / block.
__global__ __launch_bounds__(512) void k_samp(const unsigned short* __restrict__ xb,
                                              const float* __restrict__ nrm,
                                              unsigned short* __restrict__ samp) {
  __shared__ __align__(16) unsigned short Bl[64 * NK];  // 32KB
  __shared__ float ncs[64];
  const int tid = threadIdx.x;
  const int w = tid >> 6, l = tid & 63, l15 = l & 15, l4 = l >> 4;
  const int rb = blockIdx.x >> 3, ss = blockIdx.x & 7;
  const int rowbase = rb * 128 + (w >> 1) * 32;
  const int wcol = (w & 1) * 32;

  #pragma unroll
  for (int jj = 0; jj < 4; ++jj) {
    const int unit = jj * 512 + tid;
    const int sc = unit >> 5, gsl = unit & 31;
    const int s = ss * 64 + sc;
    const int jrow = s * 16 + (s & 7);
    gld16(xb + jrow * NK + gsl * 8, &Bl[unit * 8]);
  }
  if (tid < 64) {
    const int s = ss * 64 + tid;
    ncs[tid] = nrm[s * 16 + (s & 7)];
  }

  s8v A[2][8];
  #pragma unroll
  for (int rf = 0; rf < 2; ++rf) {
    const int rr = rowbase + rf * 16 + l15;
    #pragma unroll
    for (int kf = 0; kf < 8; ++kf) {
      const int g = ((kf << 2) | l4) ^ (rr & 7);
      A[rf][kf] = *reinterpret_cast<const s8v*>(xb + rr * NK + g * 8);
    }
  }
  float nr[2][4];
  #pragma unroll
  for (int rf = 0; rf < 2; ++rf)
    #pragma unroll
    for (int q = 0; q < 4; ++q) nr[rf][q] = nrm[rowbase + rf * 16 + l4 * 4 + q];

  __syncthreads();
  f32x4 acc[2][2];
  #pragma unroll
  for (int rf = 0; rf < 2; ++rf) {
    f32x4 z = {0.f, 0.f, 0.f, 0.f};
    acc[rf][0] = z; acc[rf][1] = z;
  }
  #pragma unroll
  for (int kf = 0; kf < 8; ++kf) {
    const int gs = ((kf << 2) | l4) ^ (l15 & 7);
    const s8v b0 = *reinterpret_cast<const s8v*>(&Bl[(wcol + l15) * NK + gs * 8]);
    const s8v b1 = *reinterpret_cast<const s8v*>(&Bl[(wcol + 16 + l15) * NK + gs * 8]);
    #pragma unroll
    for (int rf = 0; rf < 2; ++rf) {
      acc[rf][0] = __builtin_amdgcn_mfma_f32_16x16x32_bf16(A[rf][kf], b0, acc[rf][0], 0, 0, 0);
      acc[rf][1] = __builtin_amdgcn_mfma_f32_16x16x32_bf16(A[rf][kf], b1, acc[rf][1], 0, 0, 0);
    }
  }
  #pragma unroll
  for (int rf = 0; rf < 2; ++rf)
    #pragma unroll
    for (int cf = 0; cf < 2; ++cf) {
      const int scol = ss * 64 + wcol + cf * 16 + l15;
      const int jcol = scol * 16 + (scol & 7);
      const float nc = ncs[wcol + cf * 16 + l15];
      #pragma unroll
      for (int q = 0; q < 4; ++q) {
        const int rowg = rowbase + rf * 16 + l4 * 4 + q;
        const float sq = fmaxf(fmaf(acc[rf][cf][q], -2.0f, nr[rf][q] + nc), 0.0f);
        const float dd = __builtin_amdgcn_sqrtf(sq);
        unsigned short d16 = __half_as_ushort(__float2half(dd));
        if (jcol == rowg) d16 = 0xFFFFu;  // exclude self
        samp[rowg * SAMPN + scol] = d16;
      }
    }
}

// ----------------------------------------------------------------- k_tau ----
__global__ __launch_bounds__(256) void k_tau(const unsigned short* __restrict__ samp,
                                             unsigned* __restrict__ tauk) {
  const int w = threadIdx.x >> 6, l = threadIdx.x & 63;
  const int r = blockIdx.x * 4 + w;
  const uint4 pa = *reinterpret_cast<const uint4*>(samp + r * SAMPN + l * 8);
  unsigned v[8];
  v[0] = pa.x & 0xFFFFu; v[1] = pa.x >> 16; v[2] = pa.y & 0xFFFFu; v[3] = pa.y >> 16;
  v[4] = pa.z & 0xFFFFu; v[5] = pa.z >> 16; v[6] = pa.w & 0xFFFFu; v[7] = pa.w >> 16;
  unsigned m = 0;
  for (int pp = 0; pp < TAUR; ++pp) {
    unsigned lm = v[0];
    #pragma unroll
    for (int j = 1; j < 8; ++j) lm = umin32(lm, v[j]);
    m = lm;
    m = umin32(m, __shfl_xor(m, 1));  m = umin32(m, __shfl_xor(m, 2));
    m = umin32(m, __shfl_xor(m, 4));  m = umin32(m, __shfl_xor(m, 8));
    m = umin32(m, __shfl_xor(m, 16)); m = umin32(m, __shfl_xor(m, 32));
    const unsigned long long bal = __ballot(lm == m);
    const int owner = (int)__ffsll(bal) - 1;
    if (l == owner) {
      bool f = false;
      #pragma unroll
      for (int j = 0; j < 8; ++j)
        if (!f && v[j] == m) { v[j] = 0xFFFFFFFFu; f = true; }
    }
  }
  if (l == 0) tauk[r] = m;
}

// ---------------------------------------------------------------- k_main ----
// Barrier-free: B-fragments gathered directly from global xb (L2-resident).
// Per-lane granule offset is constant across tiles: only the column-base
// pointer advances. The gathered bytes are bitwise-identical to the staged
// path, preserving the tau guarantee vs k_samp.
__global__ __launch_bounds__(512, 4) void k_main(const unsigned short* __restrict__ xb,
                                                 const float* __restrict__ nrm,
                                                 const unsigned* __restrict__ tauk,
                                                 float* __restrict__ dnp,
                                                 unsigned* __restrict__ pass) {
  __shared__ float ncsAll[1024];   // all col norms for this slice, loaded once
  __shared__ float dpart[128];
  const int tid = threadIdx.x;
  const int w = tid >> 6, l = tid & 63, l15 = l & 15, l4 = l >> 4;
  const int rb = blockIdx.x >> 3, cs = blockIdx.x & 7;
  const int rowbase = rb * 128 + (w >> 1) * 32;
  const int wcol = (w & 1) * 32;
  const int colslice = cs * 1024;
  const unsigned long long ltm = (1ull << l) - 1ull;
  const unsigned long long sub = 0xFFFFull << (l4 * 16);

  if (tid < 128) dpart[tid] = 0.0f;
  ncsAll[tid]       = nrm[colslice + tid];
  ncsAll[tid + 512] = nrm[colslice + 512 + tid];

  s8v A[2][8];  // 32 rows x K=256 in registers, reused across all 16 col-tiles
  #pragma unroll
  for (int rf = 0; rf < 2; ++rf) {
    const int rr = rowbase + rf * 16 + l15;
    #pragma unroll
    for (int kf = 0; kf < 8; ++kf) {
      const int g = ((kf << 2) | l4) ^ (rr & 7);
      A[rf][kf] = *reinterpret_cast<const s8v*>(xb + rr * NK + g * 8);
    }
  }
  // per-lane B gather offsets (bytes), constant across tiles:
  //   off(kf) = (kf*64 ^ x64) + (l4^(l15&3))*16 + (wcol+l15)*512
  int preoff[8];
  {
    const int lowpart = ((l4 ^ (l15 & 3)) * 16) + ((wcol + l15) * 512);
    const int x64 = (l15 & 4) ? 64 : 0;
    #pragma unroll
    for (int kf = 0; kf < 8; ++kf) preoff[kf] = ((kf * 64) ^ x64) + lowpart;
  }
  const char* xbc = (const char*)xb;

  float nr[2][4], tk2[2][4], dn[2][4];
  #pragma unroll
  for (int rf = 0; rf < 2; ++rf)
    #pragma unroll
    for (int q = 0; q < 4; ++q) {
      const int rowg = rowbase + rf * 16 + l4 * 4 + q;
      nr[rf][q] = nrm[rowg];
      // widened tau: f16(tau)+1ulp as f32, squared -> filter in sq domain
      const float tw = __half2float(__ushort_as_half((unsigned short)(tauk[rowg] + 1u)));
      tk2[rf][q] = tw * tw;
      dn[rf][q] = 0.0f;
    }

  const int dtb = rowbase - colslice;                       // wave's diag tile
  const int tdw = (dtb >= 0 && dtb < 1024) ? (dtb >> 6) : -1;

  __syncthreads();   // ncsAll + dpart published; only barrier until the end

  for (int t = 0; t < 16; ++t) {
    const char* bp0 = xbc + (size_t)(colslice + t * 64) * 512;
    const int cbase = colslice + t * 64;
    f32x4 acc[2][2];
    #pragma unroll
    for (int rf = 0; rf < 2; ++rf) {
      f32x4 z = {0.f, 0.f, 0.f, 0.f};
      acc[rf][0] = z; acc[rf][1] = z;
    }
    #pragma unroll
    for (int kf = 0; kf < 8; ++kf) {
      const s8v b0 = *reinterpret_cast<const s8v*>(bp0 + preoff[kf]);
      const s8v b1 = *reinterpret_cast<const s8v*>(bp0 + 8192 + preoff[kf]);
      #pragma unroll
      for (int rf = 0; rf < 2; ++rf) {
        acc[rf][0] = __builtin_amdgcn_mfma_f32_16x16x32_bf16(A[rf][kf], b0, acc[rf][0], 0, 0, 0);
        acc[rf][1] = __builtin_amdgcn_mfma_f32_16x16x32_bf16(A[rf][kf], b1, acc[rf][1], 0, 0, 0);
      }
    }
    // epilogue: d, exp(-d) -> dn; ballot-ranked passer stores (atomic-free)
    const float nc0 = ncsAll[t * 64 + wcol + l15];
    const float nc1 = ncsAll[t * 64 + wcol + 16 + l15];
    const int colg0 = cbase + wcol + l15;
    const int colg1 = colg0 + 16;
    const int gt4 = (cs * 16 + t) * 4;
    auto epi = [&](auto dgc) {
      constexpr bool DG = decltype(dgc)::value;
      #pragma unroll
      for (int rf = 0; rf < 2; ++rf)
        #pragma unroll
        for (int q = 0; q < 4; ++q) {
          const int rowg = rowbase + rf * 16 + l4 * 4 + q;
          float sq0 = fmaf(acc[rf][0][q], -2.0f, nr[rf][q] + nc0);
          float sq1 = fmaf(acc[rf][1][q], -2.0f, nr[rf][q] + nc1);
          if (DG) { sq0 = fmaxf(sq0, 0.0f); sq1 = fmaxf(sq1, 0.0f); }
          const float d0 = __builtin_amdgcn_sqrtf(sq0);
          const float d1 = __builtin_amdgcn_sqrtf(sq1);
          float e0 = __expf(-d0), e1 = __expf(-d1);
          bool p0 = sq0 < tk2[rf][q];
          bool p1 = sq1 < tk2[rf][q];
          if (DG) {
            const bool nd0 = (rowg != colg0), nd1 = (rowg != colg1);
            e0 = nd0 ? e0 : 0.0f;  e1 = nd1 ? e1 : 0.0f;
            p0 = p0 && nd0;  p1 = p1 && nd1;
          }
          dn[rf][q] += e0 + e1;
          const unsigned long long m0 = __ballot(p0);
          const unsigned long long m1 = __ballot(p1);
          if ((m0 | m1) != 0ull) {     // wave-uniform skip
            const int r0 = __popcll(m0 & sub & ltm);  // rank in row-subgroup
            const int r1 = __popcll(m1 & sub & ltm);
            if (p0 && r0 < PSLOT) {
              const unsigned d16 = __half_as_ushort(__float2half(d0));
              pass[rowg * 512 + gt4 + r0] = (d16 << 16) | (unsigned)colg0;
            }
            if (p1 && r1 < PSLOT) {
              const unsigned d16 = __half_as_ushort(__float2half(d1));
              pass[rowg * 512 + gt4 + 2 + r1] = (d16 << 16) | (unsigned)colg1;
            }
          }
        }
    };
    if (t == tdw) epi(BoolC<true>{});
    else          epi(BoolC<false>{});
  }
  // per-row denom partial: shfl over the 16 lanes of a row, LDS-combine waves
  #pragma unroll
  for (int rf = 0; rf < 2; ++rf)
    #pragma unroll
    for (int q = 0; q < 4; ++q) {
      float vs = dn[rf][q];
      vs += __shfl_xor(vs, 1); vs += __shfl_xor(vs, 2);
      vs += __shfl_xor(vs, 4); vs += __shfl_xor(vs, 8);
      if (l15 == 0) atomicAdd(&dpart[(w >> 1) * 32 + rf * 16 + l4 * 4 + q], vs);
    }
  __syncthreads();
  if (tid < 128) dnp[(rb * 128 + tid) * 8 + cs] = dpart[tid];
}

// ----------------------------------------------------------------- k_fin ----
__global__ __launch_bounds__(256) void k_fin(const unsigned* __restrict__ pass,
                                             const float* __restrict__ dnp,
                                             const int* __restrict__ y,
                                             float* __restrict__ out) {
  const int w = threadIdx.x >> 6, l = threadIdx.x & 63;
  const int r = blockIdx.x * 4 + w;
  unsigned kk[8];
  const uint4 pa = *reinterpret_cast<const uint4*>(pass + r * 512 + l * 8);
  const uint4 pb = *reinterpret_cast<const uint4*>(pass + r * 512 + l * 8 + 4);
  kk[0] = pa.x; kk[1] = pa.y; kk[2] = pa.z; kk[3] = pa.w;
  kk[4] = pb.x; kk[5] = pb.y; kk[6] = pb.z; kk[7] = pb.w;
  unsigned myKey = 0xFFFFFFFFu;
  for (int pp = 0; pp < 16; ++pp) {
    unsigned lm = kk[0];
    #pragma unroll
    for (int j = 1; j < 8; ++j) lm = umin32(lm, kk[j]);
    unsigned m = lm;
    m = umin32(m, __shfl_xor(m, 1));  m = umin32(m, __shfl_xor(m, 2));
    m = umin32(m, __shfl_xor(m, 4));  m = umin32(m, __shfl_xor(m, 8));
    m = umin32(m, __shfl_xor(m, 16)); m = umin32(m, __shfl_xor(m, 32));
    const unsigned long long bal = __ballot(lm == m);
    const int owner = (int)__ffsll(bal) - 1;
    if (l == owner) {
      bool f = false;
      #pragma unroll
      for (int j = 0; j < 8; ++j)
        if (!f && kk[j] == m) { kk[j] = 0xFFFFFFFFu; f = true; }
    }
    if (l == pp) myKey = m;  // lanes 0..15 collect the 16 nearest keys
  }
  float den = 0.0f;
  #pragma unroll
  for (int cs = 0; cs < 8; ++cs) den += dnp[r * 8 + cs];
  const float logden = __logf(den);
  float contrib = 0.0f, cmf = 0.0f;
  if (l < 16 && myKey != 0xFFFFFFFFu) {
    const int col = (int)(myKey & 0x1FFFu);
    const float dd = __half2float(__ushort_as_half((unsigned short)(myKey >> 16)));
    if (y[col] == y[r]) { contrib = -dd - logden; cmf = 1.0f; }
  }
  contrib += __shfl_xor(contrib, 1);  contrib += __shfl_xor(contrib, 2);
  contrib += __shfl_xor(contrib, 4);  contrib += __shfl_xor(contrib, 8);
  contrib += __shfl_xor(contrib, 16); contrib += __shfl_xor(contrib, 32);
  cmf += __shfl_xor(cmf, 1);  cmf += __shfl_xor(cmf, 2);
  cmf += __shfl_xor(cmf, 4);  cmf += __shfl_xor(cmf, 8);
  cmf += __shfl_xor(cmf, 16); cmf += __shfl_xor(cmf, 32);
  if (l == 0 && cmf > 0.0f)
    atomicAdd(out, (contrib / cmf) * (-1.0f / 8192.0f));
}

// ---------------------------------------------------------------------------
extern "C" void kernel_launch(void* const* d_in, const int* in_sizes, int n_in,
                              void* d_out, int out_size, void* d_ws, size_t ws_size,
                              hipStream_t stream) {
  const float* x = (const float*)d_in[0];
  const int* y = (const int*)d_in[1];
  float* out = (float*)d_out;
  char* ws = (char*)d_ws;

  float*          dnp  = (float*)(ws + OFF_DNP);
  float*          nrm  = (float*)(ws + OFF_NRM);
  unsigned*       tauk = (unsigned*)(ws + OFF_TAU);
  unsigned short* xb   = (unsigned short*)(ws + OFF_XB);
  unsigned short* samp = (unsigned short*)(ws + OFF_SAMP);
  unsigned*       pass = (unsigned*)(ws + OFF_PASS);  // overlaps samp (after k_tau)

  k_prep<<<2048, 256, 0, stream>>>(x, xb, nrm);
  k_samp<<<512,  512, 0, stream>>>(xb, nrm, samp);
  k_tau <<<2048, 256, 0, stream>>>(samp, tauk);
  hipMemsetAsync(pass, 0xFF, PASS_BYTES, stream);   // empty-key fill (per replay)
  hipMemsetAsync(d_out, 0, sizeof(float), stream);
  k_main<<<512,  512, 0, stream>>>(xb, nrm, tauk, dnp, pass);
  k_fin <<<2048, 256, 0, stream>>>(pass, dnp, y, out);
}

// Round 7
// 118.614 us; speedup vs baseline: 1.4230x; 1.4230x over previous
//
#include <hip/hip_runtime.h>
#include <hip/hip_fp16.h>

// ---------------------------------------------------------------------------
// ClassificationKNNLoss on MI355X — fused, distance matrix never materialized.
//   k_prep : norms + bf16 convert with granule-XOR swizzle
//   k_main : full GEMM (LDS-staged B, R6 lesson: direct-global B thrashes L2);
//            branch-free epilogue: d, exp(-d)->denom; per-thread sorted top-2
//            u32 keys (f16(d)<<16|col) via umax/umin — NO tau, NO ballots,
//            NO divergent branches, NO scattered stores (R2..R5 lesson: the
//            passer machinery was the unexplained VALU/stall inflation).
//   k_fin  : per-row top-16 of 512 candidates, label match, loss reduction.
// Top-16 guarantee: union of per-(slice,wavehalf,lane) top-2 covers the true
// top-16 unless one 32-col bucket holds >=3 of them (P~0.9%/row, ~1e-4 loss).
// ---------------------------------------------------------------------------

typedef __attribute__((ext_vector_type(8))) short s8v;    // 8 x bf16 (4 VGPR)
typedef __attribute__((ext_vector_type(4))) float f32x4;  // MFMA acc

#define NROW 8192
#define NK   256

template <bool B> struct BoolC { static constexpr bool value = B; };

// ws byte offsets
#define OFF_DNP  0                          // f32[8192*8] denom partials (256KB)
#define OFF_NRM  262144                     // f32[8192]
#define OFF_XB   294912                     // u16[8192*256] swizzled bf16 (4.19MB)
#define OFF_CAND (294912 + 4194304)         // u32[8192*512] candidates (16.8MB)

__device__ __forceinline__ unsigned short f2bf(float f) {
  unsigned u = __float_as_uint(f);
  return (unsigned short)((u + 0x7FFFu + ((u >> 16) & 1u)) >> 16);  // RNE
}

__device__ __forceinline__ void gld16(const void* g, void* l) {
  __builtin_amdgcn_global_load_lds(
      (const __attribute__((address_space(1))) unsigned int*)g,
      (__attribute__((address_space(3))) unsigned int*)l, 16, 0, 0);
}

__device__ __forceinline__ unsigned umin32(unsigned a, unsigned b) { return a < b ? a : b; }
__device__ __forceinline__ unsigned umax32(unsigned a, unsigned b) { return a > b ? a : b; }

// ---------------------------------------------------------------- k_prep ----
// xb[(r,k)] stored at u16 index r*256 + ((k>>3) ^ (r&7))*8 + (k&7)
__global__ __launch_bounds__(256) void k_prep(const float* __restrict__ x,
                                              unsigned short* __restrict__ xb,
                                              float* __restrict__ nrm) {
  const int w = threadIdx.x >> 6, l = threadIdx.x & 63;
  const int r = blockIdx.x * 4 + w;
  const float4 xv = *reinterpret_cast<const float4*>(x + r * NK + l * 4);
  float ns = xv.x * xv.x + xv.y * xv.y + xv.z * xv.z + xv.w * xv.w;
  ns += __shfl_xor(ns, 1);  ns += __shfl_xor(ns, 2);  ns += __shfl_xor(ns, 4);
  ns += __shfl_xor(ns, 8);  ns += __shfl_xor(ns, 16); ns += __shfl_xor(ns, 32);
  if (l == 0) nrm[r] = ns;
  ushort4 bv;
  bv.x = f2bf(xv.x); bv.y = f2bf(xv.y); bv.z = f2bf(xv.z); bv.w = f2bf(xv.w);
  const int gs = (l >> 1) ^ (r & 7);
  *reinterpret_cast<ushort4*>(xb + r * NK + gs * 8 + (l & 1) * 4) = bv;
}

// ---------------------------------------------------------------- k_main ----
// R3/R5 geometry: 512 blocks (64 rb x 8 cs), 512 thr, 64-col tiles dbuf'd.
__global__ __launch_bounds__(512, 4) void k_main(const unsigned short* __restrict__ xb,
                                                 const float* __restrict__ nrm,
                                                 float* __restrict__ dnp,
                                                 unsigned* __restrict__ cand) {
  __shared__ __align__(16) unsigned short Bl[2][64 * NK];  // 2 x 32KB dbuf
  __shared__ float ncsAll[1024];
  __shared__ float dpart[128];
  const int tid = threadIdx.x;
  const int w = tid >> 6, l = tid & 63, l15 = l & 15, l4 = l >> 4;
  const int rb = blockIdx.x >> 3, cs = blockIdx.x & 7;
  const int rowbase = rb * 128 + (w >> 1) * 32;
  const int wcol = (w & 1) * 32;
  const int colslice = cs * 1024;

  if (tid < 128) dpart[tid] = 0.0f;
  ncsAll[tid]       = nrm[colslice + tid];
  ncsAll[tid + 512] = nrm[colslice + 512 + tid];

  s8v A[2][8];  // 32 rows x K=256 in registers, reused across all 16 col-tiles
  #pragma unroll
  for (int rf = 0; rf < 2; ++rf) {
    const int rr = rowbase + rf * 16 + l15;
    #pragma unroll
    for (int kf = 0; kf < 8; ++kf) {
      const int g = ((kf << 2) | l4) ^ (rr & 7);
      A[rf][kf] = *reinterpret_cast<const s8v*>(xb + rr * NK + g * 8);
    }
  }
  float nr[2][4], dn[2][4];
  unsigned s0[2][4], s1[2][4];  // per-thread sorted top-2 keys per row
  #pragma unroll
  for (int rf = 0; rf < 2; ++rf)
    #pragma unroll
    for (int q = 0; q < 4; ++q) {
      nr[rf][q] = nrm[rowbase + rf * 16 + l4 * 4 + q];
      dn[rf][q] = 0.0f;
      s0[rf][q] = 0xFFFFFFFFu;
      s1[rf][q] = 0xFFFFFFFFu;
    }

  auto stage = [&](int buf, int t) {
    const unsigned short* src = xb + (colslice + t * 64) * NK;  // linear 32KB
    #pragma unroll
    for (int jj = 0; jj < 4; ++jj)
      gld16(src + (jj * 512 + tid) * 8, &Bl[buf][(jj * 512 + w * 64) * 8]);
  };

  const int dtb = rowbase - colslice;                       // wave's diag tile
  const int tdw = (dtb >= 0 && dtb < 1024) ? (dtb >> 6) : -1;

  stage(0, 0);
  for (int t = 0; t < 16; ++t) {
    const int cur = t & 1;
    __syncthreads();                        // Bl[cur] ready
    if (t + 1 < 16) stage(cur ^ 1, t + 1);  // prefetch overlaps compute
    const int cbase = colslice + t * 64;
    f32x4 acc[2][2];
    #pragma unroll
    for (int rf = 0; rf < 2; ++rf) {
      f32x4 z = {0.f, 0.f, 0.f, 0.f};
      acc[rf][0] = z; acc[rf][1] = z;
    }
    #pragma unroll
    for (int kf = 0; kf < 8; ++kf) {
      const int gs = ((kf << 2) | l4) ^ (l15 & 7);
      const s8v b0 = *reinterpret_cast<const s8v*>(&Bl[cur][(wcol + l15) * NK + gs * 8]);
      const s8v b1 = *reinterpret_cast<const s8v*>(&Bl[cur][(wcol + 16 + l15) * NK + gs * 8]);
      #pragma unroll
      for (int rf = 0; rf < 2; ++rf) {
        acc[rf][0] = __builtin_amdgcn_mfma_f32_16x16x32_bf16(A[rf][kf], b0, acc[rf][0], 0, 0, 0);
        acc[rf][1] = __builtin_amdgcn_mfma_f32_16x16x32_bf16(A[rf][kf], b1, acc[rf][1], 0, 0, 0);
      }
    }
    // branch-free epilogue: d, exp(-d) -> dn; top-2 key insert (3 min/max ops)
    const float nc0 = ncsAll[t * 64 + wcol + l15];
    const float nc1 = ncsAll[t * 64 + wcol + 16 + l15];
    const unsigned colg0 = (unsigned)(cbase + wcol + l15);
    const unsigned colg1 = colg0 + 16;
    auto epi = [&](auto dgc) {
      constexpr bool DG = decltype(dgc)::value;
      #pragma unroll
      for (int rf = 0; rf < 2; ++rf)
        #pragma unroll
        for (int q = 0; q < 4; ++q) {
          const unsigned rowg = (unsigned)(rowbase + rf * 16 + l4 * 4 + q);
          float sq0 = fmaf(acc[rf][0][q], -2.0f, nr[rf][q] + nc0);
          float sq1 = fmaf(acc[rf][1][q], -2.0f, nr[rf][q] + nc1);
          if (DG) { sq0 = fmaxf(sq0, 0.0f); sq1 = fmaxf(sq1, 0.0f); }
          const float d0 = __builtin_amdgcn_sqrtf(sq0);
          const float d1 = __builtin_amdgcn_sqrtf(sq1);
          float e0 = __expf(-d0), e1 = __expf(-d1);
          unsigned k0 = ((unsigned)__half_as_ushort(__float2half(d0)) << 16) | colg0;
          unsigned k1 = ((unsigned)__half_as_ushort(__float2half(d1)) << 16) | colg1;
          if (DG) {
            const bool nd0 = (rowg != colg0), nd1 = (rowg != colg1);
            e0 = nd0 ? e0 : 0.0f;          e1 = nd1 ? e1 : 0.0f;
            k0 = nd0 ? k0 : 0xFFFFFFFFu;   k1 = nd1 ? k1 : 0xFFFFFFFFu;
          }
          dn[rf][q] += e0 + e1;
          unsigned ev = umax32(s0[rf][q], k0);
          s0[rf][q] = umin32(s0[rf][q], k0);
          s1[rf][q] = umin32(s1[rf][q], ev);
          ev = umax32(s0[rf][q], k1);
          s0[rf][q] = umin32(s0[rf][q], k1);
          s1[rf][q] = umin32(s1[rf][q], ev);
        }
    };
    if (t == tdw) epi(BoolC<true>{});
    else          epi(BoolC<false>{});
  }
  // candidate writeback: cand[row][cs][whalf][l15][2], coalesced 8B/lane
  #pragma unroll
  for (int rf = 0; rf < 2; ++rf)
    #pragma unroll
    for (int q = 0; q < 4; ++q) {
      const int rowg = rowbase + rf * 16 + l4 * 4 + q;
      uint2 pr; pr.x = s0[rf][q]; pr.y = s1[rf][q];
      *reinterpret_cast<uint2*>(&cand[rowg * 512 + cs * 64 + (w & 1) * 32 + l15 * 2]) = pr;
    }
  // per-row denom partial: shfl over the 16 lanes of a row, LDS-combine waves
  #pragma unroll
  for (int rf = 0; rf < 2; ++rf)
    #pragma unroll
    for (int q = 0; q < 4; ++q) {
      float vs = dn[rf][q];
      vs += __shfl_xor(vs, 1); vs += __shfl_xor(vs, 2);
      vs += __shfl_xor(vs, 4); vs += __shfl_xor(vs, 8);
      if (l15 == 0) atomicAdd(&dpart[(w >> 1) * 32 + rf * 16 + l4 * 4 + q], vs);
    }
  __syncthreads();
  if (tid < 128) dnp[(rb * 128 + tid) * 8 + cs] = dpart[tid];
}

// ----------------------------------------------------------------- k_fin ----
__global__ __launch_bounds__(256) void k_fin(const unsigned* __restrict__ cand,
                                             const float* __restrict__ dnp,
                                             const int* __restrict__ y,
                                             float* __restrict__ out) {
  const int w = threadIdx.x >> 6, l = threadIdx.x & 63;
  const int r = blockIdx.x * 4 + w;
  unsigned kk[8];
  const uint4 pa = *reinterpret_cast<const uint4*>(cand + r * 512 + l * 8);
  const uint4 pb = *reinterpret_cast<const uint4*>(cand + r * 512 + l * 8 + 4);
  kk[0] = pa.x; kk[1] = pa.y; kk[2] = pa.z; kk[3] = pa.w;
  kk[4] = pb.x; kk[5] = pb.y; kk[6] = pb.z; kk[7] = pb.w;
  unsigned myKey = 0xFFFFFFFFu;
  for (int pp = 0; pp < 16; ++pp) {
    unsigned lm = kk[0];
    #pragma unroll
    for (int j = 1; j < 8; ++j) lm = umin32(lm, kk[j]);
    unsigned m = lm;
    m = umin32(m, __shfl_xor(m, 1));  m = umin32(m, __shfl_xor(m, 2));
    m = umin32(m, __shfl_xor(m, 4));  m = umin32(m, __shfl_xor(m, 8));
    m = umin32(m, __shfl_xor(m, 16)); m = umin32(m, __shfl_xor(m, 32));
    const unsigned long long bal = __ballot(lm == m);
    const int owner = (int)__ffsll(bal) - 1;
    if (l == owner) {
      bool f = false;
      #pragma unroll
      for (int j = 0; j < 8; ++j)
        if (!f && kk[j] == m) { kk[j] = 0xFFFFFFFFu; f = true; }
    }
    if (l == pp) myKey = m;  // lanes 0..15 collect the 16 nearest keys
  }
  float den = 0.0f;
  #pragma unroll
  for (int cs = 0; cs < 8; ++cs) den += dnp[r * 8 + cs];
  const float logden = __logf(den);
  float contrib = 0.0f, cmf = 0.0f;
  if (l < 16 && myKey != 0xFFFFFFFFu) {
    const int col = (int)(myKey & 0x1FFFu);
    const float dd = __half2float(__ushort_as_half((unsigned short)(myKey >> 16)));
    if (y[col] == y[r]) { contrib = -dd - logden; cmf = 1.0f; }
  }
  contrib += __shfl_xor(contrib, 1);  contrib += __shfl_xor(contrib, 2);
  contrib += __shfl_xor(contrib, 4);  contrib += __shfl_xor(contrib, 8);
  contrib += __shfl_xor(contrib, 16); contrib += __shfl_xor(contrib, 32);
  cmf += __shfl_xor(cmf, 1);  cmf += __shfl_xor(cmf, 2);
  cmf += __shfl_xor(cmf, 4);  cmf += __shfl_xor(cmf, 8);
  cmf += __shfl_xor(cmf, 16); cmf += __shfl_xor(cmf, 32);
  if (l == 0 && cmf > 0.0f)
    atomicAdd(out, (contrib / cmf) * (-1.0f / 8192.0f));
}

// ---------------------------------------------------------------------------
extern "C" void kernel_launch(void* const* d_in, const int* in_sizes, int n_in,
                              void* d_out, int out_size, void* d_ws, size_t ws_size,
                              hipStream_t stream) {
  const float* x = (const float*)d_in[0];
  const int* y = (const int*)d_in[1];
  float* out = (float*)d_out;
  char* ws = (char*)d_ws;

  float*          dnp  = (float*)(ws + OFF_DNP);
  float*          nrm  = (float*)(ws + OFF_NRM);
  unsigned short* xb   = (unsigned short*)(ws + OFF_XB);
  unsigned*       cand = (unsigned*)(ws + OFF_CAND);

  hipMemsetAsync(d_out, 0, sizeof(float), stream);
  k_prep<<<2048, 256, 0, stream>>>(x, xb, nrm);
  k_main<<<512,  512, 0, stream>>>(xb, nrm, dnp, cand);
  k_fin <<<2048, 256, 0, stream>>>(cand, dnp, y, out);
}

// Round 9
// 113.818 us; speedup vs baseline: 1.4829x; 1.0421x over previous
//
#include <hip/hip_runtime.h>
#include <hip/hip_fp16.h>

// ---------------------------------------------------------------------------
// ClassificationKNNLoss on MI355X — fused, distance matrix never materialized.
//   k_prep : norms + bf16 convert with granule-XOR swizzle
//   k_main : full GEMM; branch-free epilogue (d, exp(-d)->denom, per-thread
//            sorted top-2 keys). R8: latency-bound fix — 4 barrier-independent
//            blocks/CU (64-row blocks, single-buffer 32KB LDS) + NONTEMPORAL
//            cand stores so the 16.8MB write stream stops evicting xb from L2
//            (R7: FETCH 54MB, all pipes <35%, occ 35% -> stall-dominated).
//   k_fin  : per-row top-16 of 512 candidates, label match, loss reduction.
// R8b: nontemporal builtins need native ext_vector types (not HIP uint2/4).
// ---------------------------------------------------------------------------

typedef __attribute__((ext_vector_type(8))) short s8v;       // 8 x bf16 (4 VGPR)
typedef __attribute__((ext_vector_type(4))) float f32x4;     // MFMA acc
typedef __attribute__((ext_vector_type(2))) unsigned u32x2;  // nt store
typedef __attribute__((ext_vector_type(4))) unsigned u32x4;  // nt load

#define NROW 8192
#define NK   256

template <bool B> struct BoolC { static constexpr bool value = B; };

// ws byte offsets
#define OFF_DNP  0                          // f32[8192*8] denom partials (256KB)
#define OFF_NRM  262144                     // f32[8192]
#define OFF_XB   294912                     // u16[8192*256] swizzled bf16 (4.19MB)
#define OFF_CAND (294912 + 4194304)         // u32[8192*512] candidates (16.8MB)

__device__ __forceinline__ unsigned short f2bf(float f) {
  unsigned u = __float_as_uint(f);
  return (unsigned short)((u + 0x7FFFu + ((u >> 16) & 1u)) >> 16);  // RNE
}

__device__ __forceinline__ void gld16(const void* g, void* l) {
  __builtin_amdgcn_global_load_lds(
      (const __attribute__((address_space(1))) unsigned int*)g,
      (__attribute__((address_space(3))) unsigned int*)l, 16, 0, 0);
}

__device__ __forceinline__ unsigned umin32(unsigned a, unsigned b) { return a < b ? a : b; }
__device__ __forceinline__ unsigned umax32(unsigned a, unsigned b) { return a > b ? a : b; }

// ---------------------------------------------------------------- k_prep ----
// xb[(r,k)] stored at u16 index r*256 + ((k>>3) ^ (r&7))*8 + (k&7)
__global__ __launch_bounds__(256) void k_prep(const float* __restrict__ x,
                                              unsigned short* __restrict__ xb,
                                              float* __restrict__ nrm) {
  const int w = threadIdx.x >> 6, l = threadIdx.x & 63;
  const int r = blockIdx.x * 4 + w;
  const float4 xv = *reinterpret_cast<const float4*>(x + r * NK + l * 4);
  float ns = xv.x * xv.x + xv.y * xv.y + xv.z * xv.z + xv.w * xv.w;
  ns += __shfl_xor(ns, 1);  ns += __shfl_xor(ns, 2);  ns += __shfl_xor(ns, 4);
  ns += __shfl_xor(ns, 8);  ns += __shfl_xor(ns, 16); ns += __shfl_xor(ns, 32);
  if (l == 0) nrm[r] = ns;
  ushort4 bv;
  bv.x = f2bf(xv.x); bv.y = f2bf(xv.y); bv.z = f2bf(xv.z); bv.w = f2bf(xv.w);
  const int gs = (l >> 1) ^ (r & 7);
  *reinterpret_cast<ushort4*>(xb + r * NK + gs * 8 + (l & 1) * 4) = bv;
}

// ---------------------------------------------------------------- k_main ----
// 1024 blocks = 128 rb x 8 cs; 256 thr (4 waves); 64 rows/block; 64-col tiles
// single-buffered (cross-block overlap hides stage latency at 4 blocks/CU).
__global__ __launch_bounds__(256, 4) void k_main(const unsigned short* __restrict__ xb,
                                                 const float* __restrict__ nrm,
                                                 float* __restrict__ dnp,
                                                 unsigned* __restrict__ cand) {
  __shared__ __align__(16) unsigned short Bl[64 * NK];  // 32KB single buffer
  __shared__ float ncsAll[1024];
  __shared__ float dpart[64];
  const int tid = threadIdx.x;
  const int w = tid >> 6, l = tid & 63, l15 = l & 15, l4 = l >> 4;
  const int rb = blockIdx.x >> 3, cs = blockIdx.x & 7;
  const int rowbase = rb * 64 + (w >> 1) * 32;
  const int wcol = (w & 1) * 32;
  const int colslice = cs * 1024;

  if (tid < 64) dpart[tid] = 0.0f;
  #pragma unroll
  for (int j = 0; j < 4; ++j)
    ncsAll[tid + j * 256] = nrm[colslice + tid + j * 256];

  s8v A[2][8];  // 32 rows x K=256 in registers, reused across all 16 col-tiles
  #pragma unroll
  for (int rf = 0; rf < 2; ++rf) {
    const int rr = rowbase + rf * 16 + l15;
    #pragma unroll
    for (int kf = 0; kf < 8; ++kf) {
      const int g = ((kf << 2) | l4) ^ (rr & 7);
      A[rf][kf] = *reinterpret_cast<const s8v*>(xb + rr * NK + g * 8);
    }
  }
  float nr[2][4], dn[2][4];
  unsigned s0[2][4], s1[2][4];  // per-thread sorted top-2 keys per row
  #pragma unroll
  for (int rf = 0; rf < 2; ++rf)
    #pragma unroll
    for (int q = 0; q < 4; ++q) {
      nr[rf][q] = nrm[rowbase + rf * 16 + l4 * 4 + q];
      dn[rf][q] = 0.0f;
      s0[rf][q] = 0xFFFFFFFFu;
      s1[rf][q] = 0xFFFFFFFFu;
    }

  auto stage = [&](int t) {
    const unsigned short* src = xb + (colslice + t * 64) * NK;  // linear 32KB
    #pragma unroll
    for (int jj = 0; jj < 8; ++jj)
      gld16(src + (jj * 256 + tid) * 8, &Bl[(jj * 256 + w * 64) * 8]);
  };

  const int dtb = rowbase - colslice;                       // wave's diag tile
  const int tdw = (dtb >= 0 && dtb < 1024) ? (dtb >> 6) : -1;

  for (int t = 0; t < 16; ++t) {
    stage(t);
    __syncthreads();                        // vmcnt drained: Bl ready
    const int cbase = colslice + t * 64;
    f32x4 acc[2][2];
    #pragma unroll
    for (int rf = 0; rf < 2; ++rf) {
      f32x4 z = {0.f, 0.f, 0.f, 0.f};
      acc[rf][0] = z; acc[rf][1] = z;
    }
    #pragma unroll
    for (int kf = 0; kf < 8; ++kf) {
      const int gs = ((kf << 2) | l4) ^ (l15 & 7);
      const s8v b0 = *reinterpret_cast<const s8v*>(&Bl[(wcol + l15) * NK + gs * 8]);
      const s8v b1 = *reinterpret_cast<const s8v*>(&Bl[(wcol + 16 + l15) * NK + gs * 8]);
      #pragma unroll
      for (int rf = 0; rf < 2; ++rf) {
        acc[rf][0] = __builtin_amdgcn_mfma_f32_16x16x32_bf16(A[rf][kf], b0, acc[rf][0], 0, 0, 0);
        acc[rf][1] = __builtin_amdgcn_mfma_f32_16x16x32_bf16(A[rf][kf], b1, acc[rf][1], 0, 0, 0);
      }
    }
    // branch-free epilogue: d, exp(-d) -> dn; top-2 key insert (3 min/max ops)
    const float nc0 = ncsAll[t * 64 + wcol + l15];
    const float nc1 = ncsAll[t * 64 + wcol + 16 + l15];
    const unsigned colg0 = (unsigned)(cbase + wcol + l15);
    const unsigned colg1 = colg0 + 16;
    auto epi = [&](auto dgc) {
      constexpr bool DG = decltype(dgc)::value;
      #pragma unroll
      for (int rf = 0; rf < 2; ++rf)
        #pragma unroll
        for (int q = 0; q < 4; ++q) {
          const unsigned rowg = (unsigned)(rowbase + rf * 16 + l4 * 4 + q);
          float sq0 = fmaf(acc[rf][0][q], -2.0f, nr[rf][q] + nc0);
          float sq1 = fmaf(acc[rf][1][q], -2.0f, nr[rf][q] + nc1);
          if (DG) { sq0 = fmaxf(sq0, 0.0f); sq1 = fmaxf(sq1, 0.0f); }
          const float d0 = __builtin_amdgcn_sqrtf(sq0);
          const float d1 = __builtin_amdgcn_sqrtf(sq1);
          float e0 = __expf(-d0), e1 = __expf(-d1);
          unsigned k0 = ((unsigned)__half_as_ushort(__float2half(d0)) << 16) | colg0;
          unsigned k1 = ((unsigned)__half_as_ushort(__float2half(d1)) << 16) | colg1;
          if (DG) {
            const bool nd0 = (rowg != colg0), nd1 = (rowg != colg1);
            e0 = nd0 ? e0 : 0.0f;          e1 = nd1 ? e1 : 0.0f;
            k0 = nd0 ? k0 : 0xFFFFFFFFu;   k1 = nd1 ? k1 : 0xFFFFFFFFu;
          }
          dn[rf][q] += e0 + e1;
          unsigned ev = umax32(s0[rf][q], k0);
          s0[rf][q] = umin32(s0[rf][q], k0);
          s1[rf][q] = umin32(s1[rf][q], ev);
          ev = umax32(s0[rf][q], k1);
          s0[rf][q] = umin32(s0[rf][q], k1);
          s1[rf][q] = umin32(s1[rf][q], ev);
        }
    };
    if (t == tdw) epi(BoolC<true>{});
    else          epi(BoolC<false>{});
    __syncthreads();                        // all waves done reading Bl
  }
  // candidate writeback: cand[row][cs][whalf][l15][2] — NONTEMPORAL (don't
  // evict xb from L2; the stream is read exactly once, by k_fin)
  #pragma unroll
  for (int rf = 0; rf < 2; ++rf)
    #pragma unroll
    for (int q = 0; q < 4; ++q) {
      const int rowg = rowbase + rf * 16 + l4 * 4 + q;
      u32x2 pr; pr.x = s0[rf][q]; pr.y = s1[rf][q];
      __builtin_nontemporal_store(pr,
          reinterpret_cast<u32x2*>(&cand[rowg * 512 + cs * 64 + (w & 1) * 32 + l15 * 2]));
    }
  // per-row denom partial: shfl over the 16 lanes of a row, LDS-combine waves
  #pragma unroll
  for (int rf = 0; rf < 2; ++rf)
    #pragma unroll
    for (int q = 0; q < 4; ++q) {
      float vs = dn[rf][q];
      vs += __shfl_xor(vs, 1); vs += __shfl_xor(vs, 2);
      vs += __shfl_xor(vs, 4); vs += __shfl_xor(vs, 8);
      if (l15 == 0) atomicAdd(&dpart[(w >> 1) * 32 + rf * 16 + l4 * 4 + q], vs);
    }
  __syncthreads();
  if (tid < 64) dnp[(rb * 64 + tid) * 8 + cs] = dpart[tid];
}

// ----------------------------------------------------------------- k_fin ----
__global__ __launch_bounds__(256) void k_fin(const unsigned* __restrict__ cand,
                                             const float* __restrict__ dnp,
                                             const int* __restrict__ y,
                                             float* __restrict__ out) {
  const int w = threadIdx.x >> 6, l = threadIdx.x & 63;
  const int r = blockIdx.x * 4 + w;
  unsigned kk[8];
  const u32x4 pa = __builtin_nontemporal_load(
      reinterpret_cast<const u32x4*>(cand + r * 512 + l * 8));
  const u32x4 pb = __builtin_nontemporal_load(
      reinterpret_cast<const u32x4*>(cand + r * 512 + l * 8 + 4));
  kk[0] = pa.x; kk[1] = pa.y; kk[2] = pa.z; kk[3] = pa.w;
  kk[4] = pb.x; kk[5] = pb.y; kk[6] = pb.z; kk[7] = pb.w;
  unsigned myKey = 0xFFFFFFFFu;
  for (int pp = 0; pp < 16; ++pp) {
    unsigned lm = kk[0];
    #pragma unroll
    for (int j = 1; j < 8; ++j) lm = umin32(lm, kk[j]);
    unsigned m = lm;
    m = umin32(m, __shfl_xor(m, 1));  m = umin32(m, __shfl_xor(m, 2));
    m = umin32(m, __shfl_xor(m, 4));  m = umin32(m, __shfl_xor(m, 8));
    m = umin32(m, __shfl_xor(m, 16)); m = umin32(m, __shfl_xor(m, 32));
    const unsigned long long bal = __ballot(lm == m);
    const int owner = (int)__ffsll(bal) - 1;
    if (l == owner) {
      bool f = false;
      #pragma unroll
      for (int j = 0; j < 8; ++j)
        if (!f && kk[j] == m) { kk[j] = 0xFFFFFFFFu; f = true; }
    }
    if (l == pp) myKey = m;  // lanes 0..15 collect the 16 nearest keys
  }
  float den = 0.0f;
  #pragma unroll
  for (int cs = 0; cs < 8; ++cs) den += dnp[r * 8 + cs];
  const float logden = __logf(den);
  float contrib = 0.0f, cmf = 0.0f;
  if (l < 16 && myKey != 0xFFFFFFFFu) {
    const int col = (int)(myKey & 0x1FFFu);
    const float dd = __half2float(__ushort_as_half((unsigned short)(myKey >> 16)));
    if (y[col] == y[r]) { contrib = -dd - logden; cmf = 1.0f; }
  }
  contrib += __shfl_xor(contrib, 1);  contrib += __shfl_xor(contrib, 2);
  contrib += __shfl_xor(contrib, 4);  contrib += __shfl_xor(contrib, 8);
  contrib += __shfl_xor(contrib, 16); contrib += __shfl_xor(contrib, 32);
  cmf += __shfl_xor(cmf, 1);  cmf += __shfl_xor(cmf, 2);
  cmf += __shfl_xor(cmf, 4);  cmf += __shfl_xor(cmf, 8);
  cmf += __shfl_xor(cmf, 16); cmf += __shfl_xor(cmf, 32);
  if (l == 0 && cmf > 0.0f)
    atomicAdd(out, (contrib / cmf) * (-1.0f / 8192.0f));
}

// ---------------------------------------------------------------------------
extern "C" void kernel_launch(void* const* d_in, const int* in_sizes, int n_in,
                              void* d_out, int out_size, void* d_ws, size_t ws_size,
                              hipStream_t stream) {
  const float* x = (const float*)d_in[0];
  const int* y = (const int*)d_in[1];
  float* out = (float*)d_out;
  char* ws = (char*)d_ws;

  float*          dnp  = (float*)(ws + OFF_DNP);
  float*          nrm  = (float*)(ws + OFF_NRM);
  unsigned short* xb   = (unsigned short*)(ws + OFF_XB);
  unsigned*       cand = (unsigned*)(ws + OFF_CAND);

  hipMemsetAsync(d_out, 0, sizeof(float), stream);
  k_prep<<<2048, 256, 0, stream>>>(x, xb, nrm);
  k_main<<<1024, 256, 0, stream>>>(xb, nrm, dnp, cand);
  k_fin <<<2048, 256, 0, stream>>>(cand, dnp, y, out);
}

// Round 10
// 108.156 us; speedup vs baseline: 1.5605x; 1.0523x over previous
//
#include <hip/hip_runtime.h>
#include <hip/hip_fp16.h>

// ---------------------------------------------------------------------------
// ClassificationKNNLoss on MI355X — fused, distance matrix never materialized.
//   k_prep : norms + bf16 convert with granule-XOR swizzle
//   k_main : full GEMM; branch-free epilogue (d, exp(-d)->denom, per-thread
//            sorted top-2 keys). R10: PHASE-STAGGERED tile schedule — block
//            (rb,cs) starts at tile (rb*5)&15. R9 showed all pipes <=35% with
//            identical per-block schedules: global stage/compute convoy.
//            Staggering decorrelates block phases so VALU epilogue of one
//            block overlaps staging of another on the same CU.
//   k_fin  : per-row top-16 of 512 candidates, label match, loss reduction.
// ---------------------------------------------------------------------------

typedef __attribute__((ext_vector_type(8))) short s8v;       // 8 x bf16 (4 VGPR)
typedef __attribute__((ext_vector_type(4))) float f32x4;     // MFMA acc
typedef __attribute__((ext_vector_type(2))) unsigned u32x2;  // nt store
typedef __attribute__((ext_vector_type(4))) unsigned u32x4;  // nt load

#define NROW 8192
#define NK   256

template <bool B> struct BoolC { static constexpr bool value = B; };

// ws byte offsets
#define OFF_DNP  0                          // f32[8192*8] denom partials (256KB)
#define OFF_NRM  262144                     // f32[8192]
#define OFF_XB   294912                     // u16[8192*256] swizzled bf16 (4.19MB)
#define OFF_CAND (294912 + 4194304)         // u32[8192*512] candidates (16.8MB)

__device__ __forceinline__ unsigned short f2bf(float f) {
  unsigned u = __float_as_uint(f);
  return (unsigned short)((u + 0x7FFFu + ((u >> 16) & 1u)) >> 16);  // RNE
}

__device__ __forceinline__ void gld16(const void* g, void* l) {
  __builtin_amdgcn_global_load_lds(
      (const __attribute__((address_space(1))) unsigned int*)g,
      (__attribute__((address_space(3))) unsigned int*)l, 16, 0, 0);
}

__device__ __forceinline__ unsigned umin32(unsigned a, unsigned b) { return a < b ? a : b; }
__device__ __forceinline__ unsigned umax32(unsigned a, unsigned b) { return a > b ? a : b; }

// ---------------------------------------------------------------- k_prep ----
// xb[(r,k)] stored at u16 index r*256 + ((k>>3) ^ (r&7))*8 + (k&7)
__global__ __launch_bounds__(256) void k_prep(const float* __restrict__ x,
                                              unsigned short* __restrict__ xb,
                                              float* __restrict__ nrm) {
  const int w = threadIdx.x >> 6, l = threadIdx.x & 63;
  const int r = blockIdx.x * 4 + w;
  const float4 xv = *reinterpret_cast<const float4*>(x + r * NK + l * 4);
  float ns = xv.x * xv.x + xv.y * xv.y + xv.z * xv.z + xv.w * xv.w;
  ns += __shfl_xor(ns, 1);  ns += __shfl_xor(ns, 2);  ns += __shfl_xor(ns, 4);
  ns += __shfl_xor(ns, 8);  ns += __shfl_xor(ns, 16); ns += __shfl_xor(ns, 32);
  if (l == 0) nrm[r] = ns;
  ushort4 bv;
  bv.x = f2bf(xv.x); bv.y = f2bf(xv.y); bv.z = f2bf(xv.z); bv.w = f2bf(xv.w);
  const int gs = (l >> 1) ^ (r & 7);
  *reinterpret_cast<ushort4*>(xb + r * NK + gs * 8 + (l & 1) * 4) = bv;
}

// ---------------------------------------------------------------- k_main ----
// 1024 blocks = 128 rb x 8 cs; 256 thr (4 waves); 64 rows/block; 64-col tiles
// single-buffered; per-block phase-staggered tile order.
__global__ __launch_bounds__(256, 4) void k_main(const unsigned short* __restrict__ xb,
                                                 const float* __restrict__ nrm,
                                                 float* __restrict__ dnp,
                                                 unsigned* __restrict__ cand) {
  __shared__ __align__(16) unsigned short Bl[64 * NK];  // 32KB single buffer
  __shared__ float ncsAll[1024];
  __shared__ float dpart[64];
  const int tid = threadIdx.x;
  const int w = tid >> 6, l = tid & 63, l15 = l & 15, l4 = l >> 4;
  const int rb = blockIdx.x >> 3, cs = blockIdx.x & 7;
  const int rowbase = rb * 64 + (w >> 1) * 32;
  const int wcol = (w & 1) * 32;
  const int colslice = cs * 1024;

  if (tid < 64) dpart[tid] = 0.0f;
  #pragma unroll
  for (int j = 0; j < 4; ++j)
    ncsAll[tid + j * 256] = nrm[colslice + tid + j * 256];

  s8v A[2][8];  // 32 rows x K=256 in registers, reused across all 16 col-tiles
  #pragma unroll
  for (int rf = 0; rf < 2; ++rf) {
    const int rr = rowbase + rf * 16 + l15;
    #pragma unroll
    for (int kf = 0; kf < 8; ++kf) {
      const int g = ((kf << 2) | l4) ^ (rr & 7);
      A[rf][kf] = *reinterpret_cast<const s8v*>(xb + rr * NK + g * 8);
    }
  }
  float nr[2][4], dn[2][4];
  unsigned s0[2][4], s1[2][4];  // per-thread sorted top-2 keys per row
  #pragma unroll
  for (int rf = 0; rf < 2; ++rf)
    #pragma unroll
    for (int q = 0; q < 4; ++q) {
      nr[rf][q] = nrm[rowbase + rf * 16 + l4 * 4 + q];
      dn[rf][q] = 0.0f;
      s0[rf][q] = 0xFFFFFFFFu;
      s1[rf][q] = 0xFFFFFFFFu;
    }

  auto stage = [&](int t) {
    const unsigned short* src = xb + (colslice + t * 64) * NK;  // linear 32KB
    #pragma unroll
    for (int jj = 0; jj < 8; ++jj)
      gld16(src + (jj * 256 + tid) * 8, &Bl[(jj * 256 + w * 64) * 8]);
  };

  const int dtb = rowbase - colslice;                       // wave's diag tile
  const int tdw = (dtb >= 0 && dtb < 1024) ? (dtb >> 6) : -1;
  const int t0 = (rb * 5) & 15;   // phase stagger: decorrelate block schedules

  for (int i = 0; i < 16; ++i) {
    const int t = (t0 + i) & 15;
    stage(t);
    __syncthreads();                        // vmcnt drained: Bl ready
    const int cbase = colslice + t * 64;
    f32x4 acc[2][2];
    #pragma unroll
    for (int rf = 0; rf < 2; ++rf) {
      f32x4 z = {0.f, 0.f, 0.f, 0.f};
      acc[rf][0] = z; acc[rf][1] = z;
    }
    #pragma unroll
    for (int kf = 0; kf < 8; ++kf) {
      const int gs = ((kf << 2) | l4) ^ (l15 & 7);
      const s8v b0 = *reinterpret_cast<const s8v*>(&Bl[(wcol + l15) * NK + gs * 8]);
      const s8v b1 = *reinterpret_cast<const s8v*>(&Bl[(wcol + 16 + l15) * NK + gs * 8]);
      #pragma unroll
      for (int rf = 0; rf < 2; ++rf) {
        acc[rf][0] = __builtin_amdgcn_mfma_f32_16x16x32_bf16(A[rf][kf], b0, acc[rf][0], 0, 0, 0);
        acc[rf][1] = __builtin_amdgcn_mfma_f32_16x16x32_bf16(A[rf][kf], b1, acc[rf][1], 0, 0, 0);
      }
    }
    // branch-free epilogue: d, exp(-d) -> dn; top-2 key insert (3 min/max ops)
    const float nc0 = ncsAll[t * 64 + wcol + l15];
    const float nc1 = ncsAll[t * 64 + wcol + 16 + l15];
    const unsigned colg0 = (unsigned)(cbase + wcol + l15);
    const unsigned colg1 = colg0 + 16;
    auto epi = [&](auto dgc) {
      constexpr bool DG = decltype(dgc)::value;
      #pragma unroll
      for (int rf = 0; rf < 2; ++rf)
        #pragma unroll
        for (int q = 0; q < 4; ++q) {
          const unsigned rowg = (unsigned)(rowbase + rf * 16 + l4 * 4 + q);
          float sq0 = fmaf(acc[rf][0][q], -2.0f, nr[rf][q] + nc0);
          float sq1 = fmaf(acc[rf][1][q], -2.0f, nr[rf][q] + nc1);
          if (DG) { sq0 = fmaxf(sq0, 0.0f); sq1 = fmaxf(sq1, 0.0f); }
          const float d0 = __builtin_amdgcn_sqrtf(sq0);
          const float d1 = __builtin_amdgcn_sqrtf(sq1);
          float e0 = __expf(-d0), e1 = __expf(-d1);
          unsigned k0 = ((unsigned)__half_as_ushort(__float2half(d0)) << 16) | colg0;
          unsigned k1 = ((unsigned)__half_as_ushort(__float2half(d1)) << 16) | colg1;
          if (DG) {
            const bool nd0 = (rowg != colg0), nd1 = (rowg != colg1);
            e0 = nd0 ? e0 : 0.0f;          e1 = nd1 ? e1 : 0.0f;
            k0 = nd0 ? k0 : 0xFFFFFFFFu;   k1 = nd1 ? k1 : 0xFFFFFFFFu;
          }
          dn[rf][q] += e0 + e1;
          unsigned ev = umax32(s0[rf][q], k0);
          s0[rf][q] = umin32(s0[rf][q], k0);
          s1[rf][q] = umin32(s1[rf][q], ev);
          ev = umax32(s0[rf][q], k1);
          s0[rf][q] = umin32(s0[rf][q], k1);
          s1[rf][q] = umin32(s1[rf][q], ev);
        }
    };
    if (t == tdw) epi(BoolC<true>{});
    else          epi(BoolC<false>{});
    __syncthreads();                        // all waves done reading Bl
  }
  // candidate writeback: cand[row][cs][whalf][l15][2] — NONTEMPORAL (don't
  // evict xb from L2; the stream is read exactly once, by k_fin)
  #pragma unroll
  for (int rf = 0; rf < 2; ++rf)
    #pragma unroll
    for (int q = 0; q < 4; ++q) {
      const int rowg = rowbase + rf * 16 + l4 * 4 + q;
      u32x2 pr; pr.x = s0[rf][q]; pr.y = s1[rf][q];
      __builtin_nontemporal_store(pr,
          reinterpret_cast<u32x2*>(&cand[rowg * 512 + cs * 64 + (w & 1) * 32 + l15 * 2]));
    }
  // per-row denom partial: shfl over the 16 lanes of a row, LDS-combine waves
  #pragma unroll
  for (int rf = 0; rf < 2; ++rf)
    #pragma unroll
    for (int q = 0; q < 4; ++q) {
      float vs = dn[rf][q];
      vs += __shfl_xor(vs, 1); vs += __shfl_xor(vs, 2);
      vs += __shfl_xor(vs, 4); vs += __shfl_xor(vs, 8);
      if (l15 == 0) atomicAdd(&dpart[(w >> 1) * 32 + rf * 16 + l4 * 4 + q], vs);
    }
  __syncthreads();
  if (tid < 64) dnp[(rb * 64 + tid) * 8 + cs] = dpart[tid];
}

// ----------------------------------------------------------------- k_fin ----
__global__ __launch_bounds__(256) void k_fin(const unsigned* __restrict__ cand,
                                             const float* __restrict__ dnp,
                                             const int* __restrict__ y,
                                             float* __restrict__ out) {
  const int w = threadIdx.x >> 6, l = threadIdx.x & 63;
  const int r = blockIdx.x * 4 + w;
  unsigned kk[8];
  const u32x4 pa = __builtin_nontemporal_load(
      reinterpret_cast<const u32x4*>(cand + r * 512 + l * 8));
  const u32x4 pb = __builtin_nontemporal_load(
      reinterpret_cast<const u32x4*>(cand + r * 512 + l * 8 + 4));
  kk[0] = pa.x; kk[1] = pa.y; kk[2] = pa.z; kk[3] = pa.w;
  kk[4] = pb.x; kk[5] = pb.y; kk[6] = pb.z; kk[7] = pb.w;
  unsigned myKey = 0xFFFFFFFFu;
  for (int pp = 0; pp < 16; ++pp) {
    unsigned lm = kk[0];
    #pragma unroll
    for (int j = 1; j < 8; ++j) lm = umin32(lm, kk[j]);
    unsigned m = lm;
    m = umin32(m, __shfl_xor(m, 1));  m = umin32(m, __shfl_xor(m, 2));
    m = umin32(m, __shfl_xor(m, 4));  m = umin32(m, __shfl_xor(m, 8));
    m = umin32(m, __shfl_xor(m, 16)); m = umin32(m, __shfl_xor(m, 32));
    const unsigned long long bal = __ballot(lm == m);
    const int owner = (int)__ffsll(bal) - 1;
    if (l == owner) {
      bool f = false;
      #pragma unroll
      for (int j = 0; j < 8; ++j)
        if (!f && kk[j] == m) { kk[j] = 0xFFFFFFFFu; f = true; }
    }
    if (l == pp) myKey = m;  // lanes 0..15 collect the 16 nearest keys
  }
  float den = 0.0f;
  #pragma unroll
  for (int cs = 0; cs < 8; ++cs) den += dnp[r * 8 + cs];
  const float logden = __logf(den);
  float contrib = 0.0f, cmf = 0.0f;
  if (l < 16 && myKey != 0xFFFFFFFFu) {
    const int col = (int)(myKey & 0x1FFFu);
    const float dd = __half2float(__ushort_as_half((unsigned short)(myKey >> 16)));
    if (y[col] == y[r]) { contrib = -dd - logden; cmf = 1.0f; }
  }
  contrib += __shfl_xor(contrib, 1);  contrib += __shfl_xor(contrib, 2);
  contrib += __shfl_xor(contrib, 4);  contrib += __shfl_xor(contrib, 8);
  contrib += __shfl_xor(contrib, 16); contrib += __shfl_xor(contrib, 32);
  cmf += __shfl_xor(cmf, 1);  cmf += __shfl_xor(cmf, 2);
  cmf += __shfl_xor(cmf, 4);  cmf += __shfl_xor(cmf, 8);
  cmf += __shfl_xor(cmf, 16); cmf += __shfl_xor(cmf, 32);
  if (l == 0 && cmf > 0.0f)
    atomicAdd(out, (contrib / cmf) * (-1.0f / 8192.0f));
}

// ---------------------------------------------------------------------------
extern "C" void kernel_launch(void* const* d_in, const int* in_sizes, int n_in,
                              void* d_out, int out_size, void* d_ws, size_t ws_size,
                              hipStream_t stream) {
  const float* x = (const float*)d_in[0];
  const int* y = (const int*)d_in[1];
  float* out = (float*)d_out;
  char* ws = (char*)d_ws;

  float*          dnp  = (float*)(ws + OFF_DNP);
  float*          nrm  = (float*)(ws + OFF_NRM);
  unsigned short* xb   = (unsigned short*)(ws + OFF_XB);
  unsigned*       cand = (unsigned*)(ws + OFF_CAND);

  hipMemsetAsync(d_out, 0, sizeof(float), stream);
  k_prep<<<2048, 256, 0, stream>>>(x, xb, nrm);
  k_main<<<1024, 256, 0, stream>>>(xb, nrm, dnp, cand);
  k_fin <<<2048, 256, 0, stream>>>(cand, dnp, y, out);
}